// Round 4
// baseline (5928.445 us; speedup 1.0000x reference)
//
#include <hip/hip_runtime.h>
#include <hip/hip_bf16.h>
#include <hip/hip_cooperative_groups.h>
#include <math.h>

namespace cg = cooperative_groups;

#define B_  256
#define T_  40
#define IN_ 2048
#define E_  512
#define H_  1024
#define V_  5000
#define G4_ 4096   // 4*H

typedef __bf16 bf16x8 __attribute__((ext_vector_type(8)));
typedef float  f32x4  __attribute__((ext_vector_type(4)));

__device__ __forceinline__ float sigm(float x) { return 1.0f / (1.0f + expf(-x)); }

__device__ __forceinline__ unsigned short f2b(float x) {
    __hip_bfloat16 h = __float2bfloat16(x);
    return *reinterpret_cast<unsigned short*>(&h);
}

__device__ __forceinline__ unsigned int pack2bf(float lo, float hi) {
    return (unsigned int)f2b(lo) | ((unsigned int)f2b(hi) << 16);
}

#define GLOAD_LDS(g, l) __builtin_amdgcn_global_load_lds(                     \
    (const __attribute__((address_space(1))) unsigned int*)(g),               \
    (__attribute__((address_space(3))) unsigned int*)(l), 16, 0, 0)

// ---------------------------------------------------------------------------
// bf16 MFMA GEMM: C[M,N](f32) = gather(A) @ B^T + bias[N]
//                 + addMat[(row & rowMask)*addStride + col]
// 128x128 tile, BK=32, 256 thr = 4 waves, 16x16x32 MFMA.
// ---------------------------------------------------------------------------
__global__ __launch_bounds__(256) void gemm_mfma(
    const unsigned short* __restrict__ A, int lda,
    const int* __restrict__ gidx,
    const unsigned short* __restrict__ Bm, int ldb,
    const float* __restrict__ bias,
    const float* __restrict__ addMat, int rowMask, long long addStride,
    float* __restrict__ C, int ldc, int N, int K)
{
    __shared__ unsigned short As[128 * 32];
    __shared__ unsigned short Bs[128 * 32];

    const int tid  = threadIdx.x;
    const int wave = tid >> 6, lane = tid & 63;
    const int brow0 = blockIdx.y * 128, bcol0 = blockIdx.x * 128;
    const int wrow0 = (wave >> 1) * 64, wcol0 = (wave & 1) * 64;

    const int srow = lane >> 2;
    const int scol = (lane & 3) * 8;
    const unsigned short* pA[2];
    const unsigned short* pB[2];
    unsigned short* lA[2];
    unsigned short* lB[2];
    #pragma unroll
    for (int i = 0; i < 2; ++i) {
        int seg = wave * 2 + i;
        int row = seg * 16 + srow;
        long long ar = gidx ? (long long)gidx[brow0 + row] : (long long)(brow0 + row);
        pA[i] = A + ar * lda + scol;
        pB[i] = Bm + (long long)(bcol0 + row) * ldb + scol;
        lA[i] = &As[seg * 16 * 32];
        lB[i] = &Bs[seg * 16 * 32];
    }

    f32x4 acc[4][4] = {};
    const int foff = (lane & 15) * 32 + (lane >> 4) * 8;

    for (int k0 = 0; k0 < K; k0 += 32) {
        GLOAD_LDS(pA[0] + k0, lA[0]);
        GLOAD_LDS(pA[1] + k0, lA[1]);
        GLOAD_LDS(pB[0] + k0, lB[0]);
        GLOAD_LDS(pB[1] + k0, lB[1]);
        __syncthreads();

        bf16x8 a[4], b[4];
        #pragma unroll
        for (int m = 0; m < 4; ++m)
            a[m] = *(const bf16x8*)&As[(wrow0 + m * 16) * 32 + foff];
        #pragma unroll
        for (int n = 0; n < 4; ++n)
            b[n] = *(const bf16x8*)&Bs[(wcol0 + n * 16) * 32 + foff];
        #pragma unroll
        for (int m = 0; m < 4; ++m)
            #pragma unroll
            for (int n = 0; n < 4; ++n)
                acc[m][n] = __builtin_amdgcn_mfma_f32_16x16x32_bf16(
                    a[m], b[n], acc[m][n], 0, 0, 0);
        __syncthreads();
    }

    #pragma unroll
    for (int m = 0; m < 4; ++m) {
        #pragma unroll
        for (int j = 0; j < 4; ++j) {
            int row = brow0 + wrow0 + m * 16 + (lane >> 4) * 4 + j;
            const float* addRow = addMat
                ? addMat + (long long)(row & rowMask) * addStride : nullptr;
            #pragma unroll
            for (int n = 0; n < 4; ++n) {
                int col = bcol0 + wcol0 + n * 16 + (lane & 15);
                if (col < N) {
                    float v = acc[m][n][j];
                    if (bias)   v += bias[col];
                    if (addRow) v += addRow[col];
                    C[(long long)row * ldc + col] = v;
                }
            }
        }
    }
}

// ---------------------------------------------------------------------------
// Persistent cooperative LSTM recurrence, v2 (high occupancy).
// Grid: 256 WGs x 1024 thr (16 waves). WG (mb,kb): mb in [0,4) -> 64 batch
// rows; kb in [0,64) -> 16 h-cols (gate cols {q*1024 + kb*16 + hl}).
// W_hh slice [64 gcols x 1024 K] bf16 LDS-resident (128 KB, XOR-swizzled).
// Wave (rg,cg): tile = 16 rows x 16 gate-cols where the 16 cols =
// 4 gates x 4 h-cols -> cell quad lives in 4 lanes of the same wave
// (shfl_xor exchange, no LDS roundtrip). c-state in VGPR (4x redundant).
// gates layout [T, B, 4H] f32, prefetched one step ahead.
// ---------------------------------------------------------------------------
__global__ __launch_bounds__(1024) void recur_kernel(
    unsigned short* __restrict__ hs,          // [(T+1), B, H] bf16; slot0 = 0
    const float* __restrict__ W_hh,           // [4096, 1024] f32
    const float* __restrict__ gates)          // [T, B, 4096] f32
{
    extern __shared__ unsigned short lds[];   // 64*1024 bf16 = 128 KB

    cg::grid_group grid = cg::this_grid();

    const int tid = threadIdx.x;
    const int bid = blockIdx.x;
    const int mb = bid >> 6;          // 0..3  (64 batch rows)
    const int kb = bid & 63;          // 0..63 (16 h-cols)

    // ---- stage W_hh slice into LDS once: [g=0..63][k=0..1023] bf16 ----
    // g = q*16 + hl ; global gate-row = q*1024 + kb*16 + hl
    // swizzle: 16B unit ku stored at ku ^ sw(g),  sw = (g>>4) | ((g&3)<<2)
    for (int u = tid; u < 8192; u += 1024) {
        int g  = u >> 7;               // 0..63
        int ku = u & 127;              // 16B unit within row
        int q  = g >> 4, hl = g & 15;
        const float* src = W_hh + (size_t)(q * 1024 + kb * 16 + hl) * H_ + ku * 8;
        float4 f0 = *(const float4*)src;
        float4 f1 = *(const float4*)(src + 4);
        uint4 pk;
        pk.x = pack2bf(f0.x, f0.y);
        pk.y = pack2bf(f0.z, f0.w);
        pk.z = pack2bf(f1.x, f1.y);
        pk.w = pack2bf(f1.z, f1.w);
        int sw = (g >> 4) | ((g & 3) << 2);
        int byteoff = (g << 11) + ((ku ^ sw) << 4);
        *(uint4*)((char*)lds + byteoff) = pk;
    }
    __syncthreads();

    const int wave = tid >> 6, lane = tid & 63;
    const int rg = wave & 3, cg = wave >> 2;     // row-group, col-group
    const int c = lane & 15, g4 = lane >> 4;
    const int q = c >> 2, r4 = c & 3;

    // B-fragment LDS row + swizzle
    const int ldsrow = q * 16 + cg * 4 + r4;
    const int sw = (ldsrow >> 4) | ((ldsrow & 3) << 2);
    const int brow_byte = ldsrow << 11;

    // A-fragment global offset: row = mb*64 + rg*16 + c, k-off = g4*8
    const size_t a_off = ((size_t)(mb * 64 + rg * 16 + c) << 10) + (g4 << 3);

    // cell/output coords: rows = mb*64 + rg*16 + g4*4 + j, h-col = kb*16+cg*4+r4
    const int orow0 = mb * 64 + rg * 16 + g4 * 4;
    const int hcol  = kb * 16 + cg * 4 + r4;

    // gates address base (lane's own gate column)
    const size_t g_off = ((size_t)orow0 << 12) + (q << 10) + hcol;

    float cc[4] = {0.f, 0.f, 0.f, 0.f};
    float gv[4];
    {
        const float* gp = gates + g_off;
        #pragma unroll
        for (int j = 0; j < 4; ++j) gv[j] = gp[(size_t)j << 12];
    }

    for (int t = 0; t < T_; ++t) {
        const unsigned short* hp = hs + (size_t)t * (B_ * H_) + a_off;

        f32x4 acc = {};
        #pragma unroll 8
        for (int kk = 0; kk < 32; ++kk) {
            bf16x8 a8 = *(const bf16x8*)(hp + (kk << 5));
            bf16x8 b8 = *(const bf16x8*)((const char*)lds +
                         (brow_byte + ((((kk << 2) | g4) ^ sw) << 4)));
            acc = __builtin_amdgcn_mfma_f32_16x16x32_bf16(a8, b8, acc, 0, 0, 0);
        }

        // ---- cell: gather i/f/g/o quad via shuffles, all in-wave ----
        unsigned short* hw = hs + (size_t)(t + 1) * (B_ * H_) +
                             ((size_t)orow0 << 10) + hcol;
        #pragma unroll
        for (int j = 0; j < 4; ++j) {
            float v  = acc[j] + gv[j];
            float d0 = v;
            float d1 = __shfl_xor(v, 4);
            float d2 = __shfl_xor(v, 8);
            float d3 = __shfl_xor(d1, 8);
            // d_k holds gate (q ^ k); gate m = d_{m ^ q}
            float gi = (q == 0) ? d0 : (q == 1) ? d1 : (q == 2) ? d2 : d3;
            float gf = (q == 0) ? d1 : (q == 1) ? d0 : (q == 2) ? d3 : d2;
            float gg = (q == 0) ? d2 : (q == 1) ? d3 : (q == 2) ? d0 : d1;
            float go = (q == 0) ? d3 : (q == 1) ? d2 : (q == 2) ? d1 : d0;
            float c2 = sigm(gf) * cc[j] + sigm(gi) * tanhf(gg);
            cc[j] = c2;
            if (q == 0) hw[(size_t)j << 10] = f2b(sigm(go) * tanhf(c2));
        }

        if (t + 1 < T_) {
            // prefetch next step's gates before the grid barrier
            const float* gp = gates + (size_t)(t + 1) * (B_ * G4_) + g_off;
            #pragma unroll
            for (int j = 0; j < 4; ++j) gv[j] = gp[(size_t)j << 12];
            __threadfence();
            grid.sync();
        }
    }
}

// ---------------------------------------------------------------------------
// fp32 tiled GEMM (two small GEMMs): C = A @ B^T + bias
// ---------------------------------------------------------------------------
__global__ __launch_bounds__(256) void gemm_bt(
    const float* __restrict__ A, int lda,
    const float* __restrict__ Bm, int ldb,
    const float* __restrict__ bias,
    float* __restrict__ C, int ldc, int N, int K)
{
    const int BK = 16;
    __shared__ float As[BK][64];
    __shared__ float Bs[BK][64];

    const int tx = threadIdx.x, ty = threadIdx.y;
    const int tid = ty * 16 + tx;
    const int brow0 = blockIdx.y * 64;
    const int bcol0 = blockIdx.x * 64;

    const int e0   = tid * 4;
    const int la_r = e0 / BK;
    const int la_k = e0 % BK;

    const long long arow_base = (long long)(brow0 + la_r) * lda;
    const int bRowG = bcol0 + la_r;
    const bool bValid = (bRowG < N);
    const long long brow_base = (long long)bRowG * ldb;

    float acc[4][4] = {};

    for (int k0 = 0; k0 < K; k0 += BK) {
        float4 av = *(const float4*)(A + arow_base + k0 + la_k);
        float4 bv = make_float4(0.f, 0.f, 0.f, 0.f);
        if (bValid) bv = *(const float4*)(Bm + brow_base + k0 + la_k);

        As[la_k + 0][la_r] = av.x; As[la_k + 1][la_r] = av.y;
        As[la_k + 2][la_r] = av.z; As[la_k + 3][la_r] = av.w;
        Bs[la_k + 0][la_r] = bv.x; Bs[la_k + 1][la_r] = bv.y;
        Bs[la_k + 2][la_r] = bv.z; Bs[la_k + 3][la_r] = bv.w;
        __syncthreads();

        #pragma unroll
        for (int kk = 0; kk < BK; ++kk) {
            float af[4], bf[4];
            #pragma unroll
            for (int i = 0; i < 4; ++i) af[i] = As[kk][ty * 4 + i];
            #pragma unroll
            for (int j = 0; j < 4; ++j) bf[j] = Bs[kk][tx * 4 + j];
            #pragma unroll
            for (int i = 0; i < 4; ++i)
                #pragma unroll
                for (int j = 0; j < 4; ++j)
                    acc[i][j] = fmaf(af[i], bf[j], acc[i][j]);
        }
        __syncthreads();
    }

    #pragma unroll
    for (int i = 0; i < 4; ++i) {
        const int row = brow0 + ty * 4 + i;
        #pragma unroll
        for (int j = 0; j < 4; ++j) {
            const int col = bcol0 + tx * 4 + j;
            if (col < N) {
                float v = acc[i][j];
                if (bias) v += bias[col];
                C[(long long)row * ldc + col] = v;
            }
        }
    }
}

// ---------------------------------------------------------------------------
// f32 -> bf16 conversion with optional column slice + zero row padding
// ---------------------------------------------------------------------------
__global__ void conv2bf(const float* __restrict__ src, unsigned short* __restrict__ dst,
                        int rows, int rowsPad, int cols, int srcld, int srccol0)
{
    int i = blockIdx.x * blockDim.x + threadIdx.x;
    int c4n = cols >> 2;
    if (i >= rowsPad * c4n) return;
    int r = i / c4n, c4 = i % c4n;
    ushort4 o;
    if (r < rows) {
        float4 v = *(const float4*)(src + (long long)r * srcld + srccol0 + c4 * 4);
        o.x = f2b(v.x); o.y = f2b(v.y); o.z = f2b(v.z); o.w = f2b(v.w);
    } else {
        o = make_ushort4(0, 0, 0, 0);
    }
    *(ushort4*)(dst + (long long)r * cols + c4 * 4) = o;
}

// ---------------------------------------------------------------------------
// prep: gather indices + combined bias
// idxEmb is ordered for gates rows r = t*B + b  (gates layout [T, B, 4H])
// idxLog is ordered for logits rows r = b*T + t
// ---------------------------------------------------------------------------
__global__ void prep_kernel(const int* __restrict__ labels,
                            const float* __restrict__ b_ih,
                            const float* __restrict__ b_hh,
                            int* __restrict__ idxEmb,
                            int* __restrict__ idxLog,
                            float* __restrict__ bsum)
{
    int r = blockIdx.x * blockDim.x + threadIdx.x;
    if (r < B_ * T_) {
        {   // embedding gather: r = t*B + b
            int t = r >> 8, b = r & (B_ - 1);
            int tsrc = (t == 0) ? (T_ - 1) : (t - 1);
            idxEmb[r] = labels[b * T_ + tsrc];
        }
        {   // logits gather: r = b*T + t  -> hs slot t+1
            int b = r / T_, t = r % T_;
            idxLog[r] = (t + 1) * B_ + b;
        }
    }
    if (r < G4_) bsum[r] = b_ih[r] + b_hh[r];
}

extern "C" void kernel_launch(void* const* d_in, const int* in_sizes, int n_in,
                              void* d_out, int out_size, void* d_ws, size_t ws_size,
                              hipStream_t stream)
{
    const float* X      = (const float*)d_in[0];
    const int*   labels = (const int*)  d_in[1];
    const float* W_f    = (const float*)d_in[2];
    const float* b_f    = (const float*)d_in[3];
    const float* emb    = (const float*)d_in[4];
    const float* W_ih   = (const float*)d_in[5];
    const float* W_hh   = (const float*)d_in[6];
    const float* b_ih   = (const float*)d_in[7];
    const float* b_hh   = (const float*)d_in[8];
    const float* W_out  = (const float*)d_in[9];
    const float* b_out  = (const float*)d_in[10];
    float* out = (float*)d_out;
    (void)in_sizes; (void)n_in; (void)out_size; (void)ws_size;

    char* ws = (char*)d_ws;
    size_t off = 0;
    auto alloc = [&](size_t bytes) {
        void* p = ws + off;
        off += (bytes + 255) & ~(size_t)255;
        return p;
    };
    unsigned short* emb_bf  = (unsigned short*)alloc((size_t)(V_ + 1) * E_ * 2);
    unsigned short* WihE_bf = (unsigned short*)alloc((size_t)G4_ * E_ * 2);
    unsigned short* Wout_bf = (unsigned short*)alloc((size_t)5120 * H_ * 2);
    unsigned short* hs_bf   = (unsigned short*)alloc((size_t)(T_ + 1) * B_ * H_ * 2);
    float* features = (float*)alloc(B_ * E_ * 4);
    float* bsum     = (float*)alloc(G4_ * 4);
    int*   idxEmb   = (int*)  alloc(B_ * T_ * 4);
    int*   idxLog   = (int*)  alloc(B_ * T_ * 4);

    // d_out reuse: gates [T,B,4H] at the front (fully consumed by the
    // recurrence before the logits GEMM overwrites d_out); baseMat in tail.
    float* gates   = out;
    float* baseMat = out + (size_t)B_ * T_ * G4_;   // 41.94M + 1.05M < 51.2M

    hipMemsetAsync(hs_bf, 0, B_ * H_ * 2, stream);  // h0 = 0 (slot 0)

    prep_kernel<<<(B_ * T_ + 255) / 256, 256, 0, stream>>>(
        labels, b_ih, b_hh, idxEmb, idxLog, bsum);

    {
        int n;
        n = (V_ + 1) * E_ / 4;
        conv2bf<<<(n + 255) / 256, 256, 0, stream>>>(emb, emb_bf, V_ + 1, V_ + 1, E_, E_, 0);
        n = G4_ * E_ / 4;
        conv2bf<<<(n + 255) / 256, 256, 0, stream>>>(W_ih, WihE_bf, G4_, G4_, E_, 2 * E_, E_);
        n = 5120 * H_ / 4;
        conv2bf<<<(n + 255) / 256, 256, 0, stream>>>(W_out, Wout_bf, V_, 5120, H_, H_, 0);
    }

    dim3 thr(16, 16);

    // features = X @ W_f^T + b_f            [256,512] K=2048 (fp32)
    gemm_bt<<<dim3(E_ / 64, B_ / 64), thr, 0, stream>>>(
        X, IN_, W_f, IN_, b_f, features, E_, E_, IN_);

    // base = features @ W_ih[:, :E]^T + (b_ih + b_hh)   [256,4096] K=512 (fp32)
    gemm_bt<<<dim3(G4_ / 64, B_ / 64), thr, 0, stream>>>(
        features, E_, W_ih, 2 * E_, bsum, baseMat, G4_, G4_, E_);

    // gates[t,b,:] = gather(emb_bf) @ WihE^T + base[b]   [10240,4096] K=512
    gemm_mfma<<<dim3(G4_ / 128, (B_ * T_) / 128), 256, 0, stream>>>(
        emb_bf, E_, idxEmb, WihE_bf, E_, nullptr,
        baseMat, B_ - 1, G4_, gates, G4_, G4_, E_);

    // ---- persistent cooperative recurrence (all 40 steps) ----
    {
        hipFuncSetAttribute((const void*)recur_kernel,
                            hipFuncAttributeMaxDynamicSharedMemorySize, 131072);
        void* kargs[] = { (void*)&hs_bf, (void*)&W_hh, (void*)&gates };
        hipLaunchCooperativeKernel((const void*)recur_kernel,
                                   dim3(256), dim3(1024), kargs, 131072, stream);
    }

    // logits = gather(hs_bf) @ W_out^T + b_out   [10240,5000] K=1024 (MFMA)
    gemm_mfma<<<dim3(5120 / 128, (B_ * T_) / 128), 256, 0, stream>>>(
        hs_bf, H_, idxLog, Wout_bf, H_, b_out,
        nullptr, 0, 0, out, V_, V_, H_);
}

// Round 5
// 1042.633 us; speedup vs baseline: 5.6860x; 5.6860x over previous
//
#include <hip/hip_runtime.h>
#include <hip/hip_bf16.h>
#include <math.h>

#define B_  256
#define T_  40
#define IN_ 2048
#define E_  512
#define H_  1024
#define V_  5000
#define G4_ 4096   // 4*H

typedef __bf16 bf16x8 __attribute__((ext_vector_type(8)));
typedef float  f32x4  __attribute__((ext_vector_type(4)));

__device__ __forceinline__ float sigm(float x) { return 1.0f / (1.0f + expf(-x)); }

__device__ __forceinline__ unsigned short f2b(float x) {
    __hip_bfloat16 h = __float2bfloat16(x);
    return *reinterpret_cast<unsigned short*>(&h);
}

#define GLOAD_LDS(g, l) __builtin_amdgcn_global_load_lds(                     \
    (const __attribute__((address_space(1))) unsigned int*)(g),               \
    (__attribute__((address_space(3))) unsigned int*)(l), 16, 0, 0)

// ---------------------------------------------------------------------------
// bf16 MFMA GEMM: C[M,N](f32) = gather(A) @ B^T + bias[N]
//                 + addMat[(row & rowMask)*addStride + col]
// 128x128 tile, BK=32, 256 thr = 4 waves, 16x16x32 MFMA.
// ---------------------------------------------------------------------------
__global__ __launch_bounds__(256) void gemm_mfma(
    const unsigned short* __restrict__ A, int lda,
    const int* __restrict__ gidx,
    const unsigned short* __restrict__ Bm, int ldb,
    const float* __restrict__ bias,
    const float* __restrict__ addMat, int rowMask, long long addStride,
    float* __restrict__ C, int ldc, int N, int K)
{
    __shared__ unsigned short As[128 * 32];
    __shared__ unsigned short Bs[128 * 32];

    const int tid  = threadIdx.x;
    const int wave = tid >> 6, lane = tid & 63;
    const int brow0 = blockIdx.y * 128, bcol0 = blockIdx.x * 128;
    const int wrow0 = (wave >> 1) * 64, wcol0 = (wave & 1) * 64;

    const int srow = lane >> 2;
    const int scol = (lane & 3) * 8;
    const unsigned short* pA[2];
    const unsigned short* pB[2];
    unsigned short* lA[2];
    unsigned short* lB[2];
    #pragma unroll
    for (int i = 0; i < 2; ++i) {
        int seg = wave * 2 + i;
        int row = seg * 16 + srow;
        long long ar = gidx ? (long long)gidx[brow0 + row] : (long long)(brow0 + row);
        pA[i] = A + ar * lda + scol;
        pB[i] = Bm + (long long)(bcol0 + row) * ldb + scol;
        lA[i] = &As[seg * 16 * 32];
        lB[i] = &Bs[seg * 16 * 32];
    }

    f32x4 acc[4][4] = {};
    const int foff = (lane & 15) * 32 + (lane >> 4) * 8;

    for (int k0 = 0; k0 < K; k0 += 32) {
        GLOAD_LDS(pA[0] + k0, lA[0]);
        GLOAD_LDS(pA[1] + k0, lA[1]);
        GLOAD_LDS(pB[0] + k0, lB[0]);
        GLOAD_LDS(pB[1] + k0, lB[1]);
        __syncthreads();

        bf16x8 a[4], b[4];
        #pragma unroll
        for (int m = 0; m < 4; ++m)
            a[m] = *(const bf16x8*)&As[(wrow0 + m * 16) * 32 + foff];
        #pragma unroll
        for (int n = 0; n < 4; ++n)
            b[n] = *(const bf16x8*)&Bs[(wcol0 + n * 16) * 32 + foff];
        #pragma unroll
        for (int m = 0; m < 4; ++m)
            #pragma unroll
            for (int n = 0; n < 4; ++n)
                acc[m][n] = __builtin_amdgcn_mfma_f32_16x16x32_bf16(
                    a[m], b[n], acc[m][n], 0, 0, 0);
        __syncthreads();
    }

    #pragma unroll
    for (int m = 0; m < 4; ++m) {
        #pragma unroll
        for (int j = 0; j < 4; ++j) {
            int row = brow0 + wrow0 + m * 16 + (lane >> 4) * 4 + j;
            const float* addRow = addMat
                ? addMat + (long long)(row & rowMask) * addStride : nullptr;
            #pragma unroll
            for (int n = 0; n < 4; ++n) {
                int col = bcol0 + wcol0 + n * 16 + (lane & 15);
                if (col < N) {
                    float v = acc[m][n][j];
                    if (bias)   v += bias[col];
                    if (addRow) v += addRow[col];
                    C[(long long)row * ldc + col] = v;
                }
            }
        }
    }
}

// ---------------------------------------------------------------------------
// Fused LSTM step: g = hprev @ W_hh^T + gates_t ; cell ; write hnext (bf16), c.
// Grid 256 WGs = 4 mb (64 batch rows) x 64 hb (16 h-cols). 256 thr = 4 waves.
// Wave w: rows mb*64 + w*16 .. +16, all 16 h-cols, acc[q] for 4 gates.
// A (hprev) and B (Whh rows {q*1024 + hb*16 + hl}) staged via global_load_lds
// into double-buffered LDS (BK=128), src pre-swizzled so ds_read_b128 is
// conflict-free. Cell is per-lane (lane owns the full i/f/g/o quad).
// ---------------------------------------------------------------------------
__global__ __launch_bounds__(256) void lstm_step(
    const unsigned short* __restrict__ hprev,   // [B,H] bf16
    unsigned short* __restrict__ hnext,         // [B,H] bf16
    const unsigned short* __restrict__ Whh,     // [4096,1024] bf16
    const float* __restrict__ gates_t,          // [B,4096] f32
    float* __restrict__ cbuf)                   // [B,H] f32
{
    __shared__ unsigned short ldsA[2][64][128];   // 32 KB
    __shared__ unsigned short ldsB[2][64][128];   // 32 KB

    const int tid = threadIdx.x;
    const int w = tid >> 6, lane = tid & 63;
    const int mb = blockIdx.x >> 6;      // 0..3
    const int hb = blockIdx.x & 63;      // 0..63
    const int r16 = lane & 15, g4 = lane >> 4;

    // epilogue coords: lane owns rows orow0..+4 (j), h-col hc, all 4 gates
    const int orow0 = mb * 64 + w * 16 + g4 * 4;
    const int hc    = hb * 16 + r16;

    // prefetch gates_x and c (independent of the GEMM)
    float gv[4][4];
    #pragma unroll
    for (int j = 0; j < 4; ++j) {
        const float* gp = gates_t + (size_t)(orow0 + j) * G4_ + hc;
        #pragma unroll
        for (int q = 0; q < 4; ++q) gv[q][j] = gp[q << 10];
    }
    float cold[4];
    #pragma unroll
    for (int j = 0; j < 4; ++j)
        cold[j] = cbuf[(size_t)(orow0 + j) * H_ + hc];

    // staging source pointers (pre-swizzled): wave w stages local rows
    // w*16 + i*4 + (lane>>4) of both A and B tiles; 16B per lane per instr.
    const unsigned short* srcA[4];
    const unsigned short* srcB[4];
    #pragma unroll
    for (int i = 0; i < 4; ++i) {
        int rl   = w * 16 + i * 4 + (lane >> 4);             // 0..63
        int koff = ((lane & 15) * 8) ^ ((rl & 7) * 8);       // swizzled k elem
        srcA[i] = hprev + (size_t)(mb * 64 + rl) * H_ + koff;
        srcB[i] = Whh + ((size_t)w * 1024 + hb * 16 + (rl & 15)) * H_ + koff;
    }

    f32x4 acc[4] = {};

    // K loop: 8 iterations of BK=128, double-buffered
    #define STAGE(buf, k0)                                                    \
        {                                                                     \
            _Pragma("unroll")                                                 \
            for (int i = 0; i < 4; ++i)                                       \
                GLOAD_LDS(srcA[i] + (k0), &ldsA[buf][w * 16 + i * 4][0]);     \
            _Pragma("unroll")                                                 \
            for (int i = 0; i < 4; ++i)                                       \
                GLOAD_LDS(srcB[i] + (k0), &ldsB[buf][w * 16 + i * 4][0]);     \
        }

    STAGE(0, 0);
    __syncthreads();

    for (int it = 0; it < 8; ++it) {
        const int buf = it & 1;
        if (it < 7) STAGE(buf ^ 1, (it + 1) * 128);
        #pragma unroll
        for (int ks = 0; ks < 4; ++ks) {
            const int aoff = (ks * 32 + g4 * 8) ^ ((r16 & 7) * 8);
            bf16x8 a8 = *(const bf16x8*)&ldsA[buf][w * 16 + r16][aoff];
            #pragma unroll
            for (int q = 0; q < 4; ++q) {
                bf16x8 b8 = *(const bf16x8*)&ldsB[buf][q * 16 + r16][aoff];
                acc[q] = __builtin_amdgcn_mfma_f32_16x16x32_bf16(
                    a8, b8, acc[q], 0, 0, 0);
            }
        }
        __syncthreads();
    }
    #undef STAGE

    // ---- fused cell: lane has i/f/g/o for 4 rows x 1 h-col ----
    #pragma unroll
    for (int j = 0; j < 4; ++j) {
        float gi = acc[0][j] + gv[0][j];
        float gf = acc[1][j] + gv[1][j];
        float gg = acc[2][j] + gv[2][j];
        float go = acc[3][j] + gv[3][j];
        float c2 = sigm(gf) * cold[j] + sigm(gi) * tanhf(gg);
        cbuf[(size_t)(orow0 + j) * H_ + hc] = c2;
        hnext[(size_t)(orow0 + j) * H_ + hc] = f2b(sigm(go) * tanhf(c2));
    }
}

// ---------------------------------------------------------------------------
// fp32 tiled GEMM (two small GEMMs): C = A @ B^T + bias
// ---------------------------------------------------------------------------
__global__ __launch_bounds__(256) void gemm_bt(
    const float* __restrict__ A, int lda,
    const float* __restrict__ Bm, int ldb,
    const float* __restrict__ bias,
    float* __restrict__ C, int ldc, int N, int K)
{
    const int BK = 16;
    __shared__ float As[BK][64];
    __shared__ float Bs[BK][64];

    const int tx = threadIdx.x, ty = threadIdx.y;
    const int tid = ty * 16 + tx;
    const int brow0 = blockIdx.y * 64;
    const int bcol0 = blockIdx.x * 64;

    const int e0   = tid * 4;
    const int la_r = e0 / BK;
    const int la_k = e0 % BK;

    const long long arow_base = (long long)(brow0 + la_r) * lda;
    const int bRowG = bcol0 + la_r;
    const bool bValid = (bRowG < N);
    const long long brow_base = (long long)bRowG * ldb;

    float acc[4][4] = {};

    for (int k0 = 0; k0 < K; k0 += BK) {
        float4 av = *(const float4*)(A + arow_base + k0 + la_k);
        float4 bv = make_float4(0.f, 0.f, 0.f, 0.f);
        if (bValid) bv = *(const float4*)(Bm + brow_base + k0 + la_k);

        As[la_k + 0][la_r] = av.x; As[la_k + 1][la_r] = av.y;
        As[la_k + 2][la_r] = av.z; As[la_k + 3][la_r] = av.w;
        Bs[la_k + 0][la_r] = bv.x; Bs[la_k + 1][la_r] = bv.y;
        Bs[la_k + 2][la_r] = bv.z; Bs[la_k + 3][la_r] = bv.w;
        __syncthreads();

        #pragma unroll
        for (int kk = 0; kk < BK; ++kk) {
            float af[4], bf[4];
            #pragma unroll
            for (int i = 0; i < 4; ++i) af[i] = As[kk][ty * 4 + i];
            #pragma unroll
            for (int j = 0; j < 4; ++j) bf[j] = Bs[kk][tx * 4 + j];
            #pragma unroll
            for (int i = 0; i < 4; ++i)
                #pragma unroll
                for (int j = 0; j < 4; ++j)
                    acc[i][j] = fmaf(af[i], bf[j], acc[i][j]);
        }
        __syncthreads();
    }

    #pragma unroll
    for (int i = 0; i < 4; ++i) {
        const int row = brow0 + ty * 4 + i;
        #pragma unroll
        for (int j = 0; j < 4; ++j) {
            const int col = bcol0 + tx * 4 + j;
            if (col < N) {
                float v = acc[i][j];
                if (bias) v += bias[col];
                C[(long long)row * ldc + col] = v;
            }
        }
    }
}

// ---------------------------------------------------------------------------
// f32 -> bf16 conversion with optional column slice + zero row padding
// ---------------------------------------------------------------------------
__global__ void conv2bf(const float* __restrict__ src, unsigned short* __restrict__ dst,
                        int rows, int rowsPad, int cols, int srcld, int srccol0)
{
    int i = blockIdx.x * blockDim.x + threadIdx.x;
    int c4n = cols >> 2;
    if (i >= rowsPad * c4n) return;
    int r = i / c4n, c4 = i % c4n;
    ushort4 o;
    if (r < rows) {
        float4 v = *(const float4*)(src + (long long)r * srcld + srccol0 + c4 * 4);
        o.x = f2b(v.x); o.y = f2b(v.y); o.z = f2b(v.z); o.w = f2b(v.w);
    } else {
        o = make_ushort4(0, 0, 0, 0);
    }
    *(ushort4*)(dst + (long long)r * cols + c4 * 4) = o;
}

// ---------------------------------------------------------------------------
// prep: gather indices + combined bias
// idxEmb ordered for gates rows r = t*B + b (gates layout [T, B, 4H])
// idxLog ordered for logits rows r = b*T + t
// ---------------------------------------------------------------------------
__global__ void prep_kernel(const int* __restrict__ labels,
                            const float* __restrict__ b_ih,
                            const float* __restrict__ b_hh,
                            int* __restrict__ idxEmb,
                            int* __restrict__ idxLog,
                            float* __restrict__ bsum)
{
    int r = blockIdx.x * blockDim.x + threadIdx.x;
    if (r < B_ * T_) {
        {   // embedding gather: r = t*B + b
            int t = r >> 8, b = r & (B_ - 1);
            int tsrc = (t == 0) ? (T_ - 1) : (t - 1);
            idxEmb[r] = labels[b * T_ + tsrc];
        }
        {   // logits gather: r = b*T + t  -> hs slot t+1
            int b = r / T_, t = r % T_;
            idxLog[r] = (t + 1) * B_ + b;
        }
    }
    if (r < G4_) bsum[r] = b_ih[r] + b_hh[r];
}

extern "C" void kernel_launch(void* const* d_in, const int* in_sizes, int n_in,
                              void* d_out, int out_size, void* d_ws, size_t ws_size,
                              hipStream_t stream)
{
    const float* X      = (const float*)d_in[0];
    const int*   labels = (const int*)  d_in[1];
    const float* W_f    = (const float*)d_in[2];
    const float* b_f    = (const float*)d_in[3];
    const float* emb    = (const float*)d_in[4];
    const float* W_ih   = (const float*)d_in[5];
    const float* W_hh   = (const float*)d_in[6];
    const float* b_ih   = (const float*)d_in[7];
    const float* b_hh   = (const float*)d_in[8];
    const float* W_out  = (const float*)d_in[9];
    const float* b_out  = (const float*)d_in[10];
    float* out = (float*)d_out;
    (void)in_sizes; (void)n_in; (void)out_size; (void)ws_size;

    char* ws = (char*)d_ws;
    size_t off = 0;
    auto alloc = [&](size_t bytes) {
        void* p = ws + off;
        off += (bytes + 255) & ~(size_t)255;
        return p;
    };
    unsigned short* emb_bf  = (unsigned short*)alloc((size_t)(V_ + 1) * E_ * 2);
    unsigned short* WihE_bf = (unsigned short*)alloc((size_t)G4_ * E_ * 2);
    unsigned short* Whh_bf  = (unsigned short*)alloc((size_t)G4_ * H_ * 2);
    unsigned short* Wout_bf = (unsigned short*)alloc((size_t)5120 * H_ * 2);
    unsigned short* hs_bf   = (unsigned short*)alloc((size_t)(T_ + 1) * B_ * H_ * 2);
    float* features = (float*)alloc(B_ * E_ * 4);
    float* cbuf     = (float*)alloc(B_ * H_ * 4);
    float* bsum     = (float*)alloc(G4_ * 4);
    int*   idxEmb   = (int*)  alloc(B_ * T_ * 4);
    int*   idxLog   = (int*)  alloc(B_ * T_ * 4);

    // d_out reuse: gates [T,B,4H] at the front (fully consumed by the
    // recurrence before the logits GEMM overwrites d_out); baseMat in tail.
    float* gates   = out;
    float* baseMat = out + (size_t)B_ * T_ * G4_;   // 41.94M + 1.05M < 51.2M

    hipMemsetAsync(hs_bf, 0, B_ * H_ * 2, stream);  // h0 = 0 (slot 0)
    hipMemsetAsync(cbuf, 0, B_ * H_ * 4, stream);   // c0 = 0

    prep_kernel<<<(B_ * T_ + 255) / 256, 256, 0, stream>>>(
        labels, b_ih, b_hh, idxEmb, idxLog, bsum);

    {
        int n;
        n = (V_ + 1) * E_ / 4;
        conv2bf<<<(n + 255) / 256, 256, 0, stream>>>(emb, emb_bf, V_ + 1, V_ + 1, E_, E_, 0);
        n = G4_ * E_ / 4;
        conv2bf<<<(n + 255) / 256, 256, 0, stream>>>(W_ih, WihE_bf, G4_, G4_, E_, 2 * E_, E_);
        n = G4_ * H_ / 4;
        conv2bf<<<(n + 255) / 256, 256, 0, stream>>>(W_hh, Whh_bf, G4_, G4_, H_, H_, 0);
        n = 5120 * H_ / 4;
        conv2bf<<<(n + 255) / 256, 256, 0, stream>>>(W_out, Wout_bf, V_, 5120, H_, H_, 0);
    }

    dim3 thr(16, 16);

    // features = X @ W_f^T + b_f            [256,512] K=2048 (fp32)
    gemm_bt<<<dim3(E_ / 64, B_ / 64), thr, 0, stream>>>(
        X, IN_, W_f, IN_, b_f, features, E_, E_, IN_);

    // base = features @ W_ih[:, :E]^T + (b_ih + b_hh)   [256,4096] K=512 (fp32)
    gemm_bt<<<dim3(G4_ / 64, B_ / 64), thr, 0, stream>>>(
        features, E_, W_ih, 2 * E_, bsum, baseMat, G4_, G4_, E_);

    // gates[t,b,:] = gather(emb_bf) @ WihE^T + base[b]   [10240,4096] K=512
    gemm_mfma<<<dim3(G4_ / 128, (B_ * T_) / 128), 256, 0, stream>>>(
        emb_bf, E_, idxEmb, WihE_bf, E_, nullptr,
        baseMat, B_ - 1, G4_, gates, G4_, G4_, E_);

    // ---- recurrence: 40 fused step launches ----
    for (int t = 0; t < T_; ++t) {
        lstm_step<<<256, 256, 0, stream>>>(
            hs_bf + (size_t)t * B_ * H_,
            hs_bf + (size_t)(t + 1) * B_ * H_,
            Whh_bf,
            gates + (size_t)t * B_ * G4_,
            cbuf);
    }

    // logits = gather(hs_bf) @ W_out^T + b_out   [10240,5000] K=1024 (MFMA)
    gemm_mfma<<<dim3(5120 / 128, (B_ * T_) / 128), 256, 0, stream>>>(
        hs_bf, H_, idxLog, Wout_bf, H_, b_out,
        nullptr, 0, 0, out, V_, V_, H_);
}